// Round 14
// baseline (184.372 us; speedup 1.0000x reference)
//
#include <hip/hip_runtime.h>
#include <math.h>

#define Bb   2
#define CIN  32
#define Gg   4
#define NH   4
#define Hh   28
#define Ww   28
#define HW   784
#define Pp   7
#define PP   49
#define MID  48
#define COUT 64
#define OC   192   // MID*NH

// workspace offsets (floats); Q/K/V/O all [bh][g][ij][c] row-major
#define QOFF  0
#define KOFF  1204224
#define VOFF  2408448
#define OOFF  3612672

// 1/sqrt(32) * log2(e): scores pre-scaled by log2e so softmax exp is a bare
// v_exp_f32 (2^x) — exact softmax invariance.
#define KSCALE 0.2550611135387359f

// small precomputed tables (recomputed every call by the table block of qkvpe)
__device__ unsigned g_peT2[Gg * PP * 16];   // [v][kl][cpair(16)] — b128/lane coalesced
__device__ unsigned g_geT2[8 * 64];         // [cpair(8)][v*16+g*4+m], scaled
__device__ float    g_WT2[OC * COUT];       // [h*48+c][o], permuted Wout

typedef _Float16 h2f __attribute__((ext_vector_type(2)));

__device__ __forceinline__ unsigned packh2(float a, float b) {
    auto r = __builtin_amdgcn_cvt_pkrtz(a, b);    // v_cvt_pkrtz_f16_f32
    return __builtin_bit_cast(unsigned, r);
}

__device__ __forceinline__ float fdot2(unsigned a, unsigned b, float c) {
    return __builtin_amdgcn_fdot2(__builtin_bit_cast(h2f, a),
                                  __builtin_bit_cast(h2f, b), c, false);
}

__device__ __forceinline__ float exp2_fast(float x) {   // 2^x, exp2(-inf)=0
    float r;
    asm("v_exp_f32 %0, %1" : "=v"(r) : "v"(x));
    return r;
}

// ---------------------------------------------------------------- kernel 1
// fused QKV 1x1 conv (blocks 0..447, half-rows of 14) + table setup (block 448)
__global__ __launch_bounds__(192) void qkvpe_kernel(const float* __restrict__ x,
    const float* __restrict__ Wq, const float* __restrict__ bq,
    const float* __restrict__ Wk, const float* __restrict__ bk,
    const float* __restrict__ Wv, const float* __restrict__ bv,
    const float* row_w1, const float* row_b1,
    const float* row_g,  const float* row_bb,
    const float* row_w2, const float* row_b2,
    const float* col_w1, const float* col_b1,
    const float* col_g,  const float* col_bb,
    const float* col_w2, const float* col_b2,
    const float* row_idx, const float* col_idx,
    const float* group_emb, const int* g_indices,
    const float* Wout,
    float* __restrict__ ws)
{
    __shared__ float xs[CIN * 16];                // conv path (padded stride 16)
    __shared__ float wtmp[16 * 193];              // table path: Wout transpose staging
    int tid = threadIdx.x;
    if (blockIdx.x == Bb * Gg * Hh * 2) {
        // ---------------- table block ----------------
        for (int t = tid; t < 2 * Gg * PP; t += 192) {
            int half = t / (Gg * PP);
            int n    = t - half * (Gg * PP);      // v*49 + kl
            int v = n / PP, kl = n % PP;
            const float* w1 = half ? col_w1 : row_w1;
            const float* b1 = half ? col_b1 : row_b1;
            const float* lg = half ? col_g  : row_g;
            const float* lb = half ? col_bb : row_bb;
            const float* w2 = half ? col_w2 : row_w2;
            const float* b2 = half ? col_b2 : row_b2;
            float tv = half ? col_idx[n] : row_idx[n];

            float hb[16];
            float mean = 0.f;
            for (int k = 0; k < 16; k++) { hb[k] = tv * w1[k] + b1[k]; mean += hb[k]; }
            mean *= (1.f / 16.f);
            float var = 0.f;
            for (int k = 0; k < 16; k++) { float d = hb[k] - mean; var += d * d; }
            var *= (1.f / 16.f);
            float inv = 1.f / sqrtf(var + 1e-5f);
            for (int k = 0; k < 16; k++) {
                float hn = (hb[k] - mean) * inv * lg[k] + lb[k];
                hb[k] = hn / (1.f + expf(-hn));
            }
            float accv[16];
            for (int p = 0; p < 16; p++) {
                float acc = b2[p];
                for (int k = 0; k < 16; k++) acc += hb[k] * w2[p * 16 + k];
                accv[p] = acc * KSCALE;
            }
            for (int i2 = 0; i2 < 8; i2++)
                g_peT2[(v * PP + kl) * 16 + half * 8 + i2] =
                    packh2(accv[2 * i2], accv[2 * i2 + 1]);
        }
        for (int t = tid; t < 64; t += 192) {
            int gi = g_indices[t];
            for (int i2 = 0; i2 < 8; i2++)
                g_geT2[i2 * 64 + t] = packh2(group_emb[gi * 16 + 2 * i2] * KSCALE,
                                             group_emb[gi * 16 + 2 * i2 + 1] * KSCALE);
        }
        // g_WT2[tp*64+o] = Wout[o*192 + c*4+h] via LDS transpose
        for (int chunk = 0; chunk < 4; chunk++) {
            int obase = chunk * 16;
            __syncthreads();
            for (int idx = tid; idx < 16 * OC; idx += 192) {
                int ol = idx / OC, t = idx % OC;
                wtmp[ol * 193 + t] = Wout[(obase + ol) * OC + t];   // coalesced
            }
            __syncthreads();
            for (int idx = tid; idx < 16 * OC; idx += 192) {
                int tp = idx / 16, ol = idx % 16;                   // ol fastest
                int h = tp / MID, c = tp % MID;
                g_WT2[tp * 64 + obase + ol] = wtmp[ol * 193 + c * NH + h];
            }
        }
        return;
    }

    // ---------------- QKV block: one (b,g,i) half-row of 14 ----------------
    int r = blockIdx.x;
    int jh = r & 1; r >>= 1;
    int i = r % Hh; r /= Hh;
    int g = r & 3;  int b = r >> 2;
    int j0 = jh * 14;

    for (int idx = tid; idx < CIN * 14; idx += 192) {
        int ci = idx / 14, jj = idx % 14;
        xs[ci * 16 + jj] = x[((b * CIN + ci) * Gg + g) * HW + i * Ww + j0 + jj];
    }
    __syncthreads();

    int h = tid / MID, c = tid % MID;
    int oo = c * NH + h;                          // original channel index
    int wbase = (((b * NH + h) * Gg + g) * HW + i * Ww + j0) * MID + c;

    const float* Wm[3]  = {Wq, Wk, Wv};
    const float* bm[3]  = {bq, bk, bv};
    const int    off[3] = {QOFF, KOFF, VOFF};
    const float  scl[3] = {1.0f, KSCALE, 1.0f};
    for (int p = 0; p < 3; p++) {
        const float4* Wr4 = (const float4*)(Wm[p] + oo * CIN);   // 8 float4 / row
        float bias = bm[p][oo];
        float a[14];
        #pragma unroll
        for (int j = 0; j < 14; j++) a[j] = bias;

        #pragma unroll 2
        for (int ci8 = 0; ci8 < 8; ci8++) {
            float4 wv4 = Wr4[ci8];                // global load, L1-hot
            int cb = ci8 * 4;
#define CHAN(WV, CI)                                                          \
            {                                                                 \
                float wv = WV;                                                \
                float4 xA = *(const float4*)&xs[(CI) * 16 + 0];               \
                float4 xB = *(const float4*)&xs[(CI) * 16 + 4];               \
                float4 xC = *(const float4*)&xs[(CI) * 16 + 8];               \
                float2 xD = *(const float2*)&xs[(CI) * 16 + 12];              \
                a[0] += wv * xA.x;  a[1] += wv * xA.y;                        \
                a[2] += wv * xA.z;  a[3] += wv * xA.w;                        \
                a[4] += wv * xB.x;  a[5] += wv * xB.y;                        \
                a[6] += wv * xB.z;  a[7] += wv * xB.w;                        \
                a[8] += wv * xC.x;  a[9] += wv * xC.y;                        \
                a[10] += wv * xC.z; a[11] += wv * xC.w;                       \
                a[12] += wv * xD.x; a[13] += wv * xD.y;                       \
            }
            CHAN(wv4.x, cb + 0)
            CHAN(wv4.y, cb + 1)
            CHAN(wv4.z, cb + 2)
            CHAN(wv4.w, cb + 3)
#undef CHAN
        }
        float s = scl[p];
        #pragma unroll
        for (int j = 0; j < 14; j++) ws[off[p] + wbase + j * MID] = a[j] * s;
    }
}

// ---------------------------------------------------------------- kernel 2
// attention: block = 4 waves = positions (i, j0..j0+3) for one (b,h).
// K and V staged in m-PAIR HALVES so LDS fits 6 blocks/CU (24.5 KB vs r13's
// 39.9 KB / 4 blocks): 1568 blocks / 1536 resident = single scheduling
// generation, 24 waves/CU latency hiding. 7 barriers (vs 3) — r7/r8 showed
// stage granularity ~neutral at fixed residency; residency is the lever.
__global__ __launch_bounds__(256, 4) void attn_kernel(float* __restrict__ ws)
{
    __shared__ __align__(16) unsigned kvb[3780];        // 15120 B: K-half [2][cell][27] / V-half [cell][52]
    __shared__ __align__(16) unsigned pp2[4][2][PP][4]; //  6272 B: [wave][mp][kl][v] f16 m-pair probs
    __shared__ __align__(16) unsigned qp[4][4][32];     //  2048 B: [wave][g][cpair 24, pad 32]
    __shared__ __align__(16) float gsm[4][64];          //  1024 B: [wave][vg*4+m]

    const int tid  = threadIdx.x;
    const int wave = tid >> 6;
    const int lane = tid & 63;

    int blk = blockIdx.x;                  // ((bh)*28 + i)*7 + j0/4
    int j0 = (blk % 7) * 4;
    int i  = (blk / 7) % Hh;
    int bh = blk / (7 * Hh);
    int b = bh >> 2, h = bh & 3;
    int j  = j0 + wave;
    int ij = i * Ww + j;

    const float* Qt  = ws + QOFF;
    const float* Kbh = ws + KOFF + (size_t)bh * Gg * HW * MID;
    const float* Vbh = ws + VOFF + (size_t)bh * Gg * HW * MID;
    float* Ot = ws + OOFF;

    // ---- q packed f16 pairs into per-wave LDS ----
    if (lane < 48) {
        int g = lane / 12, c4 = lane % 12;
        float4 qv = *(const float4*)&Qt[((size_t)(bh * Gg + g) * HW + ij) * MID + c4 * 4];
        qp[wave][g][c4 * 2]     = packh2(qv.x, qv.y);
        qp[wave][g][c4 * 2 + 1] = packh2(qv.z, qv.w);
    }

#define STAGE_K(HALF)                                                           \
    for (int t = tid; t < 1680; t += 256) {                                     \
        int c4 = t % 12; int cell = (t / 12) % 70; int ml = t / 840;            \
        int gy = i - 3 + cell / 10, gx = j0 - 3 + cell % 10;                    \
        float4 val = {0.f, 0.f, 0.f, 0.f};                                      \
        if ((unsigned)gy < Hh && (unsigned)gx < Ww)                             \
            val = *(const float4*)&Kbh[((size_t)(((HALF) * 2 + ml) * HW         \
                                        + gy * Ww + gx)) * MID + c4 * 4];       \
        *(uint2*)&kvb[(ml * 70 + cell) * 27 + c4 * 2] =                         \
            make_uint2(packh2(val.x, val.y), packh2(val.z, val.w));             \
    }

#define CONTENT(HALF)                                                           \
    _Pragma("unroll 2")                                                         \
    for (int u4 = 0; u4 < 6; u4++) {                                            \
        uint4 qA = *(const uint4*)&qp[wave][0][u4 * 4];                         \
        uint4 qB = *(const uint4*)&qp[wave][1][u4 * 4];                         \
        uint4 qC = *(const uint4*)&qp[wave][2][u4 * 4];                         \
        uint4 qD = *(const uint4*)&qp[wave][3][u4 * 4];                         \
        _Pragma("unroll")                                                       \
        for (int ml = 0; ml < 2; ml++) {                                        \
            int m = (HALF) * 2 + ml;                                            \
            int base = (ml * 70 + cell) * 27 + u4 * 4;                          \
            uint2 k01 = *(const uint2*)&kvb[base];                              \
            uint2 k23 = *(const uint2*)&kvb[base + 2];                          \
            acc[m][0] = fdot2(k23.y, qA.w, fdot2(k23.x, qA.z, fdot2(k01.y, qA.y, fdot2(k01.x, qA.x, acc[m][0])))); \
            acc[m][1] = fdot2(k23.y, qB.w, fdot2(k23.x, qB.z, fdot2(k01.y, qB.y, fdot2(k01.x, qB.x, acc[m][1])))); \
            acc[m][2] = fdot2(k23.y, qC.w, fdot2(k23.x, qC.z, fdot2(k01.y, qC.y, fdot2(k01.x, qC.x, acc[m][2])))); \
            acc[m][3] = fdot2(k23.y, qD.w, fdot2(k23.x, qD.z, fdot2(k01.y, qD.y, fdot2(k01.x, qD.x, acc[m][3])))); \
        }                                                                       \
    }

#define STAGE_V(PAIR)                                                           \
    for (int t = tid; t < 840; t += 256) {                                      \
        int c4 = t % 12; int cl = t / 12;                                       \
        int gy = i - 3 + cl / 10, gx = j0 - 3 + cl % 10;                        \
        float4 v0 = {0.f,0.f,0.f,0.f}, v1 = v0;                                 \
        if ((unsigned)gy < Hh && (unsigned)gx < Ww) {                           \
            const float* vp = &Vbh[((size_t)((PAIR) * 2 * HW + gy * Ww + gx))   \
                                   * MID + c4 * 4];                             \
            v0 = *(const float4*)vp;                                            \
            v1 = *(const float4*)(vp + (size_t)HW * MID);                       \
        }                                                                       \
        uint4 w;                                                                \
        w.x = packh2(v0.x, v1.x); w.y = packh2(v0.y, v1.y);                     \
        w.z = packh2(v0.z, v1.z); w.w = packh2(v0.w, v1.w);                     \
        *(uint4*)&kvb[cl * 52 + c4 * 4] = w;                                    \
    }

#define PV_PASS(PAIR)                                                           \
    if (lane < MID) {                                                           \
        for (int kk2 = 0; kk2 < Pp; kk2++) {                                    \
            _Pragma("unroll")                                                   \
            for (int ll2 = 0; ll2 < Pp; ll2++) {                                \
                int kl2  = kk2 * Pp + ll2;                                      \
                int cell2 = kk2 * 10 + ll2 + wave;                              \
                unsigned vv = kvb[cell2 * 52 + lane];                           \
                uint4 A = *(const uint4*)&pp2[wave][PAIR][kl2][0];              \
                o0 = fdot2(vv, A.x, o0);                                        \
                o1 = fdot2(vv, A.y, o1);                                        \
                o2 = fdot2(vv, A.z, o2);                                        \
                o3 = fdot2(vv, A.w, o3);                                        \
            }                                                                   \
        }                                                                       \
    }

    // ---- stage K half 0 (m0,m1) ----
    STAGE_K(0)

    // ---- per-lane geometry (lane = kl) ----
    int kk = lane / Pp, ll = lane % Pp;
    int cell = (lane < PP) ? kk * 10 + ll + wave : 0;
    bool vmask = (lane < PP) && ((unsigned)(i + kk - 3) < Hh) && ((unsigned)(j + ll - 3) < Ww);
    int lclamp = lane < PP ? lane : 0;

    // ---- pe scores in registers; b128 q broadcasts + coalesced b128 peT2 ----
    float per[4][4] = {};                          // [v][g]
    #pragma unroll
    for (int u4 = 0; u4 < 4; u4++) {               // 4 cpairs per iter (c 0..31)
        uint4 qA = *(const uint4*)&qp[wave][0][u4 * 4];
        uint4 qB = *(const uint4*)&qp[wave][1][u4 * 4];
        uint4 qC = *(const uint4*)&qp[wave][2][u4 * 4];
        uint4 qD = *(const uint4*)&qp[wave][3][u4 * 4];
        #pragma unroll
        for (int v = 0; v < 4; v++) {
            uint4 pk = *(const uint4*)&g_peT2[(v * PP + lclamp) * 16 + u4 * 4];
            per[v][0] = fdot2(pk.w, qA.w, fdot2(pk.z, qA.z, fdot2(pk.y, qA.y, fdot2(pk.x, qA.x, per[v][0]))));
            per[v][1] = fdot2(pk.w, qB.w, fdot2(pk.z, qB.z, fdot2(pk.y, qB.y, fdot2(pk.x, qB.x, per[v][1]))));
            per[v][2] = fdot2(pk.w, qC.w, fdot2(pk.z, qC.z, fdot2(pk.y, qC.y, fdot2(pk.x, qC.x, per[v][2]))));
            per[v][3] = fdot2(pk.w, qD.w, fdot2(pk.z, qD.z, fdot2(pk.y, qD.y, fdot2(pk.x, qD.x, per[v][3]))));
        }
    }
    // fold border/idle mask into per: exp2(-inf) = 0
    if (!vmask) {
        #pragma unroll
        for (int v = 0; v < 4; v++)
            #pragma unroll
            for (int g = 0; g < 4; g++) per[v][g] = -INFINITY;
    }

    // ---- group scores: lane = vg*4+m; q pairs 16..23 (c 32..47) ----
    {
        int g = (lane >> 2) & 3;
        float ga = 0.f;
        #pragma unroll
        for (int u = 0; u < 8; u++)
            ga = fdot2(g_geT2[u * 64 + lane], qp[wave][g][16 + u], ga);
        gsm[wave][lane] = ga;
    }

    float acc[4][4] = {};                          // [m][g]
    __syncthreads();                               // B1: K01 ready
    CONTENT(0)
    __syncthreads();                               // B2: K01 readers done
    STAGE_K(1)
    __syncthreads();                               // B3: K23 ready
    CONTENT(1)

    // ---- softmax per (v,g); bare v_exp_f32 (log2e pre-folded) ----
    float ppr[4][4] = {};                          // [v][m]
    #pragma unroll
    for (int v = 0; v < 4; v++) {
        #pragma unroll
        for (int g = 0; g < 4; g++) {
            int vg = v * 4 + g;
            float4 gs = *(const float4*)&gsm[wave][vg * 4];   // b128 broadcast
            float ex[4];
            ex[0] = exp2_fast(acc[0][g] + per[v][g] + gs.x);
            ex[1] = exp2_fast(acc[1][g] + per[v][g] + gs.y);
            ex[2] = exp2_fast(acc[2][g] + per[v][g] + gs.z);
            ex[3] = exp2_fast(acc[3][g] + per[v][g] + gs.w);
            float ls = ex[0] + ex[1] + ex[2] + ex[3];
            #pragma unroll
            for (int d = 32; d > 0; d >>= 1) ls += __shfl_xor(ls, d, 64);
            float rinv = 1.0f / ls;
            #pragma unroll
            for (int m = 0; m < 4; m++) ppr[v][m] += ex[m] * rinv;
        }
    }
    // pack probs as f16 m-pairs: pp2[wave][mp][kl][v]
    if (lane < PP) {
        uint4 w0, w1;
        w0.x = packh2(ppr[0][0], ppr[0][1]); w0.y = packh2(ppr[1][0], ppr[1][1]);
        w0.z = packh2(ppr[2][0], ppr[2][1]); w0.w = packh2(ppr[3][0], ppr[3][1]);
        w1.x = packh2(ppr[0][2], ppr[0][3]); w1.y = packh2(ppr[1][2], ppr[1][3]);
        w1.z = packh2(ppr[2][2], ppr[2][3]); w1.w = packh2(ppr[3][2], ppr[3][3]);
        *(uint4*)&pp2[wave][0][lane][0] = w0;
        *(uint4*)&pp2[wave][1][lane][0] = w1;
    }

    float o0 = 0.f, o1 = 0.f, o2 = 0.f, o3 = 0.f;
    __syncthreads();                               // B4: K23 readers done, pp2 visible
    STAGE_V(0)
    __syncthreads();                               // B5: V01 ready
    PV_PASS(0)
    __syncthreads();                               // B6: V01 readers done
    STAGE_V(1)
    __syncthreads();                               // B7: V23 ready
    PV_PASS(1)

    if (lane < MID) {
        Ot[((size_t)(b * Gg + 0) * HW + ij) * OC + h * MID + lane] = o0;
        Ot[((size_t)(b * Gg + 1) * HW + ij) * OC + h * MID + lane] = o1;
        Ot[((size_t)(b * Gg + 2) * HW + ij) * OC + h * MID + lane] = o2;
        Ot[((size_t)(b * Gg + 3) * HW + ij) * OC + h * MID + lane] = o3;
    }
#undef STAGE_K
#undef CONTENT
#undef STAGE_V
#undef PV_PASS
}

// ---------------------------------------------------------------- kernel 3
__global__ __launch_bounds__(256) void outproj_kernel(const float* __restrict__ bout,
                                                      const float* __restrict__ ws,
                                                      float* __restrict__ out)
{
    __shared__ float ov[16 * 193];
    __shared__ float res[64 * 17];
    int tid = threadIdx.x;
    int p0 = blockIdx.x * 16;
    const float* Ot = ws + OOFF;

    for (int idx = tid; idx < 16 * OC; idx += 256) {
        int pl = idx / OC, t = idx % OC;
        ov[pl * 193 + t] = Ot[(size_t)(p0 + pl) * OC + t];
    }
    __syncthreads();

    int o = tid & 63, pg = tid >> 6;
    float a0 = bout[o], a1 = a0, a2 = a0, a3 = a0;
    for (int t = 0; t < OC; t++) {
        float w = g_WT2[t * 64 + o];
        a0 += w * ov[(pg     ) * 193 + t];
        a1 += w * ov[(pg +  4) * 193 + t];
        a2 += w * ov[(pg +  8) * 193 + t];
        a3 += w * ov[(pg + 12) * 193 + t];
    }
    res[o * 17 + pg     ] = a0;
    res[o * 17 + pg +  4] = a1;
    res[o * 17 + pg +  8] = a2;
    res[o * 17 + pg + 12] = a3;
    __syncthreads();

    for (int idx = tid; idx < 1024; idx += 256) {
        int o2 = idx >> 4, pl = idx & 15;
        int p = p0 + pl;
        int ij2 = p % HW; int bv = p / HW; int v = bv & 3; int bb = bv >> 2;
        out[((bb * COUT + o2) * Gg + v) * HW + ij2] = res[o2 * 17 + pl];
    }
}

// ---------------------------------------------------------------- launch
extern "C" void kernel_launch(void* const* d_in, const int* in_sizes, int n_in,
                              void* d_out, int out_size, void* d_ws, size_t ws_size,
                              hipStream_t stream)
{
    const float* x      = (const float*)d_in[0];
    const float* Wq     = (const float*)d_in[1];
    const float* bq     = (const float*)d_in[2];
    const float* Wk     = (const float*)d_in[3];
    const float* bk     = (const float*)d_in[4];
    const float* Wv     = (const float*)d_in[5];
    const float* bv     = (const float*)d_in[6];
    const float* Wout   = (const float*)d_in[7];
    const float* bout   = (const float*)d_in[8];
    const float* row_w1 = (const float*)d_in[9];
    const float* row_b1 = (const float*)d_in[10];
    const float* row_g  = (const float*)d_in[11];
    const float* row_bb = (const float*)d_in[12];
    const float* row_w2 = (const float*)d_in[13];
    const float* row_b2 = (const float*)d_in[14];
    const float* col_w1 = (const float*)d_in[15];
    const float* col_b1 = (const float*)d_in[16];
    const float* col_g  = (const float*)d_in[17];
    const float* col_bb = (const float*)d_in[18];
    const float* col_w2 = (const float*)d_in[19];
    const float* col_b2 = (const float*)d_in[20];
    const float* gemb   = (const float*)d_in[21];
    const float* ridx   = (const float*)d_in[22];
    const float* cidx   = (const float*)d_in[23];
    const int*   gidx   = (const int*)d_in[24];

    float* ws  = (float*)d_ws;
    float* out = (float*)d_out;

    qkvpe_kernel<<<Bb * Gg * Hh * 2 + 1, 192, 0, stream>>>(
        x, Wq, bq, Wk, bk, Wv, bv,
        row_w1, row_b1, row_g, row_bb, row_w2, row_b2,
        col_w1, col_b1, col_g, col_bb, col_w2, col_b2,
        ridx, cidx, gemb, gidx, Wout, ws);
    attn_kernel<<<Bb * NH * Hh * (Ww / 4), 256, 0, stream>>>(ws);
    outproj_kernel<<<Bb * Gg * HW / 16, 256, 0, stream>>>(bout, ws, out);
}

// Round 15
// 173.957 us; speedup vs baseline: 1.0599x; 1.0599x over previous
//
#include <hip/hip_runtime.h>
#include <math.h>

#define Bb   2
#define CIN  32
#define Gg   4
#define NH   4
#define Hh   28
#define Ww   28
#define HW   784
#define Pp   7
#define PP   49
#define MID  48
#define COUT 64
#define OC   192   // MID*NH

// workspace offsets (floats); Q/K/V/O all [bh][g][ij][c] row-major
#define QOFF  0
#define KOFF  1204224
#define VOFF  2408448
#define OOFF  3612672

// 1/sqrt(32) * log2(e): scores pre-scaled by log2e so softmax exp is a bare
// v_exp_f32 (2^x) — exact softmax invariance.
#define KSCALE 0.2550611135387359f

// small precomputed tables (recomputed every call by the table block of qkvpe)
__device__ unsigned g_peT2[Gg * PP * 16];   // [v][kl][cpair(16)] — b128/lane coalesced
__device__ unsigned g_geT2[8 * 64];         // [cpair(8)][v*16+g*4+m], scaled
__device__ float    g_WT2[OC * COUT];       // [h*48+c][o], permuted Wout

typedef _Float16 h2f __attribute__((ext_vector_type(2)));

__device__ __forceinline__ unsigned packh2(float a, float b) {
    auto r = __builtin_amdgcn_cvt_pkrtz(a, b);    // v_cvt_pkrtz_f16_f32
    return __builtin_bit_cast(unsigned, r);
}

__device__ __forceinline__ float fdot2(unsigned a, unsigned b, float c) {
    return __builtin_amdgcn_fdot2(__builtin_bit_cast(h2f, a),
                                  __builtin_bit_cast(h2f, b), c, false);
}

__device__ __forceinline__ float exp2_fast(float x) {   // 2^x, exp2(-inf)=0
    float r;
    asm("v_exp_f32 %0, %1" : "=v"(r) : "v"(x));
    return r;
}

// ---------------------------------------------------------------- kernel 1
// fused QKV 1x1 conv (blocks 0..447, half-rows of 14) + table setup (block 448)
__global__ __launch_bounds__(192) void qkvpe_kernel(const float* __restrict__ x,
    const float* __restrict__ Wq, const float* __restrict__ bq,
    const float* __restrict__ Wk, const float* __restrict__ bk,
    const float* __restrict__ Wv, const float* __restrict__ bv,
    const float* row_w1, const float* row_b1,
    const float* row_g,  const float* row_bb,
    const float* row_w2, const float* row_b2,
    const float* col_w1, const float* col_b1,
    const float* col_g,  const float* col_bb,
    const float* col_w2, const float* col_b2,
    const float* row_idx, const float* col_idx,
    const float* group_emb, const int* g_indices,
    const float* Wout,
    float* __restrict__ ws)
{
    __shared__ float xs[CIN * 16];                // conv path (padded stride 16)
    __shared__ float wtmp[16 * 193];              // table path: Wout transpose staging
    int tid = threadIdx.x;
    if (blockIdx.x == Bb * Gg * Hh * 2) {
        // ---------------- table block ----------------
        for (int t = tid; t < 2 * Gg * PP; t += 192) {
            int half = t / (Gg * PP);
            int n    = t - half * (Gg * PP);      // v*49 + kl
            int v = n / PP, kl = n % PP;
            const float* w1 = half ? col_w1 : row_w1;
            const float* b1 = half ? col_b1 : row_b1;
            const float* lg = half ? col_g  : row_g;
            const float* lb = half ? col_bb : row_bb;
            const float* w2 = half ? col_w2 : row_w2;
            const float* b2 = half ? col_b2 : row_b2;
            float tv = half ? col_idx[n] : row_idx[n];

            float hb[16];
            float mean = 0.f;
            for (int k = 0; k < 16; k++) { hb[k] = tv * w1[k] + b1[k]; mean += hb[k]; }
            mean *= (1.f / 16.f);
            float var = 0.f;
            for (int k = 0; k < 16; k++) { float d = hb[k] - mean; var += d * d; }
            var *= (1.f / 16.f);
            float inv = 1.f / sqrtf(var + 1e-5f);
            for (int k = 0; k < 16; k++) {
                float hn = (hb[k] - mean) * inv * lg[k] + lb[k];
                hb[k] = hn / (1.f + expf(-hn));
            }
            float accv[16];
            for (int p = 0; p < 16; p++) {
                float acc = b2[p];
                for (int k = 0; k < 16; k++) acc += hb[k] * w2[p * 16 + k];
                accv[p] = acc * KSCALE;
            }
            for (int i2 = 0; i2 < 8; i2++)
                g_peT2[(v * PP + kl) * 16 + half * 8 + i2] =
                    packh2(accv[2 * i2], accv[2 * i2 + 1]);
        }
        for (int t = tid; t < 64; t += 192) {
            int gi = g_indices[t];
            for (int i2 = 0; i2 < 8; i2++)
                g_geT2[i2 * 64 + t] = packh2(group_emb[gi * 16 + 2 * i2] * KSCALE,
                                             group_emb[gi * 16 + 2 * i2 + 1] * KSCALE);
        }
        // g_WT2[tp*64+o] = Wout[o*192 + c*4+h] via LDS transpose
        for (int chunk = 0; chunk < 4; chunk++) {
            int obase = chunk * 16;
            __syncthreads();
            for (int idx = tid; idx < 16 * OC; idx += 192) {
                int ol = idx / OC, t = idx % OC;
                wtmp[ol * 193 + t] = Wout[(obase + ol) * OC + t];   // coalesced
            }
            __syncthreads();
            for (int idx = tid; idx < 16 * OC; idx += 192) {
                int tp = idx / 16, ol = idx % 16;                   // ol fastest
                int h = tp / MID, c = tp % MID;
                g_WT2[tp * 64 + obase + ol] = wtmp[ol * 193 + c * NH + h];
            }
        }
        return;
    }

    // ---------------- QKV block: one (b,g,i) half-row of 14 ----------------
    int r = blockIdx.x;
    int jh = r & 1; r >>= 1;
    int i = r % Hh; r /= Hh;
    int g = r & 3;  int b = r >> 2;
    int j0 = jh * 14;

    for (int idx = tid; idx < CIN * 14; idx += 192) {
        int ci = idx / 14, jj = idx % 14;
        xs[ci * 16 + jj] = x[((b * CIN + ci) * Gg + g) * HW + i * Ww + j0 + jj];
    }
    __syncthreads();

    int h = tid / MID, c = tid % MID;
    int oo = c * NH + h;                          // original channel index
    int wbase = (((b * NH + h) * Gg + g) * HW + i * Ww + j0) * MID + c;

    const float* Wm[3]  = {Wq, Wk, Wv};
    const float* bm[3]  = {bq, bk, bv};
    const int    off[3] = {QOFF, KOFF, VOFF};
    const float  scl[3] = {1.0f, KSCALE, 1.0f};
    for (int p = 0; p < 3; p++) {
        const float4* Wr4 = (const float4*)(Wm[p] + oo * CIN);   // 8 float4 / row
        float bias = bm[p][oo];
        float a[14];
        #pragma unroll
        for (int j = 0; j < 14; j++) a[j] = bias;

        #pragma unroll 2
        for (int ci8 = 0; ci8 < 8; ci8++) {
            float4 wv4 = Wr4[ci8];                // global load, L1-hot
            int cb = ci8 * 4;
#define CHAN(WV, CI)                                                          \
            {                                                                 \
                float wv = WV;                                                \
                float4 xA = *(const float4*)&xs[(CI) * 16 + 0];               \
                float4 xB = *(const float4*)&xs[(CI) * 16 + 4];               \
                float4 xC = *(const float4*)&xs[(CI) * 16 + 8];               \
                float2 xD = *(const float2*)&xs[(CI) * 16 + 12];              \
                a[0] += wv * xA.x;  a[1] += wv * xA.y;                        \
                a[2] += wv * xA.z;  a[3] += wv * xA.w;                        \
                a[4] += wv * xB.x;  a[5] += wv * xB.y;                        \
                a[6] += wv * xB.z;  a[7] += wv * xB.w;                        \
                a[8] += wv * xC.x;  a[9] += wv * xC.y;                        \
                a[10] += wv * xC.z; a[11] += wv * xC.w;                       \
                a[12] += wv * xD.x; a[13] += wv * xD.y;                       \
            }
            CHAN(wv4.x, cb + 0)
            CHAN(wv4.y, cb + 1)
            CHAN(wv4.z, cb + 2)
            CHAN(wv4.w, cb + 3)
#undef CHAN
        }
        float s = scl[p];
        #pragma unroll
        for (int j = 0; j < 14; j++) ws[off[p] + wbase + j * MID] = a[j] * s;
    }
}

// ---------------------------------------------------------------- kernel 2
// attention: block = 4 waves = positions (i, j0..j0+3) for one (b,h).
// ROUND-13 structure (best measured: 49.1 us) — r14's m-pair-half split
// (6 blocks/CU, 7 barriers) regressed: barriers cost more than residency won.
// Only change vs r13: K staging computes slot geometry once and reuses it
// across the 4 m loads (divides /4, 4 loads issued back-to-back).
__global__ __launch_bounds__(256, 4) void attn_kernel(float* __restrict__ ws)
{
    __shared__ __align__(16) unsigned kvb[7560];   // 30240 B: K [m][cell][27]; V [cell][c][2]
    __shared__ __align__(16) unsigned pp2[4][PP][8];   // 6272 B: [wave][kl][v*2+mp] f16-pair probs
    __shared__ __align__(16) unsigned qp[4][4][32];    // 2048 B: [wave][g][cpair 24, pad to 32]
    __shared__ __align__(16) float gsm[4][64];     //  1024 B: [wave][vg*4+m]

    const int tid  = threadIdx.x;
    const int wave = tid >> 6;
    const int lane = tid & 63;

    int blk = blockIdx.x;                  // ((bh)*28 + i)*7 + j0/4
    int j0 = (blk % 7) * 4;
    int i  = (blk / 7) % Hh;
    int bh = blk / (7 * Hh);
    int b = bh >> 2, h = bh & 3;
    int j  = j0 + wave;
    int ij = i * Ww + j;

    const float* Qt  = ws + QOFF;
    const float* Kbh = ws + KOFF + (size_t)bh * Gg * HW * MID;
    const float* Vbh = ws + VOFF + (size_t)bh * Gg * HW * MID;
    float* Ot = ws + OOFF;

    // ---- q packed f16 pairs into per-wave LDS (scale folded into K/peT/geT) ----
    if (lane < 48) {
        int g = lane / 12, c4 = lane % 12;
        float4 qv = *(const float4*)&Qt[((size_t)(bh * Gg + g) * HW + ij) * MID + c4 * 4];
        qp[wave][g][c4 * 2]     = packh2(qv.x, qv.y);
        qp[wave][g][c4 * 2 + 1] = packh2(qv.z, qv.w);
    }

    // ---- stage all-m K tile as f16 pairs, cell-major, stride 27.
    //      Slot geometry computed once, reused for all 4 m. ----
    #pragma unroll
    for (int s = 0; s < 4; s++) {
        int t = tid + s * 256;
        if (t < 840) {
            int c4 = t % 12, cl = t / 12;
            int gy = i - 3 + cl / 10, gx = j0 - 3 + cl % 10;
            bool ok = ((unsigned)gy < Hh) && ((unsigned)gx < Ww);
            const float* kp = &Kbh[(size_t)(gy * Ww + gx) * MID + c4 * 4];
            #pragma unroll
            for (int m = 0; m < 4; m++) {
                float4 val = {0.f, 0.f, 0.f, 0.f};
                if (ok) val = *(const float4*)(kp + (size_t)m * HW * MID);
                *(uint2*)&kvb[(m * 70 + cl) * 27 + c4 * 2] =
                    make_uint2(packh2(val.x, val.y), packh2(val.z, val.w));
            }
        }
    }

    // ---- per-lane geometry (lane = kl) ----
    int kk = lane / Pp, ll = lane % Pp;
    int cell = (lane < PP) ? kk * 10 + ll + wave : 0;
    bool vmask = (lane < PP) && ((unsigned)(i + kk - 3) < Hh) && ((unsigned)(j + ll - 3) < Ww);
    int lclamp = lane < PP ? lane : 0;

    // ---- pe scores in registers; b128 q broadcasts + coalesced b128 peT2 ----
    float per[4][4] = {};                          // [v][g]
    #pragma unroll
    for (int u4 = 0; u4 < 4; u4++) {               // 4 cpairs per iter (c 0..31)
        uint4 qA = *(const uint4*)&qp[wave][0][u4 * 4];
        uint4 qB = *(const uint4*)&qp[wave][1][u4 * 4];
        uint4 qC = *(const uint4*)&qp[wave][2][u4 * 4];
        uint4 qD = *(const uint4*)&qp[wave][3][u4 * 4];
        #pragma unroll
        for (int v = 0; v < 4; v++) {
            uint4 pk = *(const uint4*)&g_peT2[(v * PP + lclamp) * 16 + u4 * 4];
            per[v][0] = fdot2(pk.w, qA.w, fdot2(pk.z, qA.z, fdot2(pk.y, qA.y, fdot2(pk.x, qA.x, per[v][0]))));
            per[v][1] = fdot2(pk.w, qB.w, fdot2(pk.z, qB.z, fdot2(pk.y, qB.y, fdot2(pk.x, qB.x, per[v][1]))));
            per[v][2] = fdot2(pk.w, qC.w, fdot2(pk.z, qC.z, fdot2(pk.y, qC.y, fdot2(pk.x, qC.x, per[v][2]))));
            per[v][3] = fdot2(pk.w, qD.w, fdot2(pk.z, qD.z, fdot2(pk.y, qD.y, fdot2(pk.x, qD.x, per[v][3]))));
        }
    }
    // fold the border/idle mask into per: exp2(-inf) = 0, so no per-term select
    if (!vmask) {
        #pragma unroll
        for (int v = 0; v < 4; v++)
            #pragma unroll
            for (int g = 0; g < 4; g++) per[v][g] = -INFINITY;
    }

    // ---- group scores: lane = vg*4+m; q pairs 16..23 (c 32..47) ----
    {
        int g = (lane >> 2) & 3;
        float ga = 0.f;
        #pragma unroll
        for (int u = 0; u < 8; u++)
            ga = fdot2(g_geT2[u * 64 + lane], qp[wave][g][16 + u], ga);
        gsm[wave][lane] = ga;
    }
    __syncthreads();                               // barrier 1: K tile ready

    // ---- content: b128 q broadcasts, b64 K reads; each K pair serves all 4 g ----
    float acc[4][4] = {};                          // [m][g]
    #pragma unroll 2
    for (int u4 = 0; u4 < 6; u4++) {               // 4 cpairs (8 channels) per iter
        uint4 qA = *(const uint4*)&qp[wave][0][u4 * 4];
        uint4 qB = *(const uint4*)&qp[wave][1][u4 * 4];
        uint4 qC = *(const uint4*)&qp[wave][2][u4 * 4];
        uint4 qD = *(const uint4*)&qp[wave][3][u4 * 4];
        #pragma unroll
        for (int m = 0; m < 4; m++) {
            int base = (m * 70 + cell) * 27 + u4 * 4;
            uint2 k01 = *(const uint2*)&kvb[base];
            uint2 k23 = *(const uint2*)&kvb[base + 2];
            acc[m][0] = fdot2(k23.y, qA.w, fdot2(k23.x, qA.z, fdot2(k01.y, qA.y, fdot2(k01.x, qA.x, acc[m][0]))));
            acc[m][1] = fdot2(k23.y, qB.w, fdot2(k23.x, qB.z, fdot2(k01.y, qB.y, fdot2(k01.x, qB.x, acc[m][1]))));
            acc[m][2] = fdot2(k23.y, qC.w, fdot2(k23.x, qC.z, fdot2(k01.y, qC.y, fdot2(k01.x, qC.x, acc[m][2]))));
            acc[m][3] = fdot2(k23.y, qD.w, fdot2(k23.x, qD.z, fdot2(k01.y, qD.y, fdot2(k01.x, qD.x, acc[m][3]))));
        }
    }

    // ---- softmax per (v,g); scores pre-scaled by log2e -> bare v_exp_f32 ----
    float ppr[4][4] = {};                          // [v][m]
    #pragma unroll
    for (int v = 0; v < 4; v++) {
        #pragma unroll
        for (int g = 0; g < 4; g++) {
            int vg = v * 4 + g;
            float4 gs = *(const float4*)&gsm[wave][vg * 4];   // b128 broadcast
            float ex[4];
            ex[0] = exp2_fast(acc[0][g] + per[v][g] + gs.x);
            ex[1] = exp2_fast(acc[1][g] + per[v][g] + gs.y);
            ex[2] = exp2_fast(acc[2][g] + per[v][g] + gs.z);
            ex[3] = exp2_fast(acc[3][g] + per[v][g] + gs.w);
            float ls = ex[0] + ex[1] + ex[2] + ex[3];
            #pragma unroll
            for (int d = 32; d > 0; d >>= 1) ls += __shfl_xor(ls, d, 64);
            float rinv = 1.0f / ls;
            #pragma unroll
            for (int m = 0; m < 4; m++) ppr[v][m] += ex[m] * rinv;
        }
    }
    // pack probs as f16 m-pairs: pp2[wave][kl][v*2+mp]
    if (lane < PP) {
        uint4 w0, w1;
        w0.x = packh2(ppr[0][0], ppr[0][1]); w0.y = packh2(ppr[0][2], ppr[0][3]);
        w0.z = packh2(ppr[1][0], ppr[1][1]); w0.w = packh2(ppr[1][2], ppr[1][3]);
        w1.x = packh2(ppr[2][0], ppr[2][1]); w1.y = packh2(ppr[2][2], ppr[2][3]);
        w1.z = packh2(ppr[3][0], ppr[3][1]); w1.w = packh2(ppr[3][2], ppr[3][3]);
        *(uint4*)&pp2[wave][lane][0] = w0;
        *(uint4*)&pp2[wave][lane][4] = w1;
    }
    __syncthreads();                               // barrier 2: K reads done

    // ---- stage all-m V as f16, u32 idx = (cell*48+c)*2 + p (m-pair plane) ----
    for (int t = tid; t < 840; t += 256) {
        int c4 = t % 12; int cl = t / 12;
        int gy = i - 3 + cl / 10, gx = j0 - 3 + cl % 10;
        float4 v0 = {0.f,0.f,0.f,0.f}, v1 = v0, v2 = v0, v3 = v0;
        if ((unsigned)gy < Hh && (unsigned)gx < Ww) {
            const float* vp = &Vbh[((size_t)(gy * Ww + gx)) * MID + c4 * 4];
            v0 = *(const float4*)vp;
            v1 = *(const float4*)(vp + (size_t)HW * MID);
            v2 = *(const float4*)(vp + (size_t)2 * HW * MID);
            v3 = *(const float4*)(vp + (size_t)3 * HW * MID);
        }
        uint4 wA, wB;
        wA.x = packh2(v0.x, v1.x); wA.y = packh2(v2.x, v3.x);
        wA.z = packh2(v0.y, v1.y); wA.w = packh2(v2.y, v3.y);
        wB.x = packh2(v0.z, v1.z); wB.y = packh2(v2.z, v3.z);
        wB.z = packh2(v0.w, v1.w); wB.w = packh2(v2.w, v3.w);
        *(uint4*)&kvb[(cl * 48 + c4 * 4) * 2    ] = wA;
        *(uint4*)&kvb[(cl * 48 + c4 * 4) * 2 + 4] = wB;
    }
    __syncthreads();                               // barrier 3: V tile ready

    // ---- PV: lane = c (<48); one b64 V read + 2 b128 prob broadcasts per cell ----
    if (lane < MID) {
        float o0 = 0.f, o1 = 0.f, o2 = 0.f, o3 = 0.f;
        const uint4* ppw = (const uint4*)&pp2[wave][0][0];
        for (int kk2 = 0; kk2 < Pp; kk2++) {
            #pragma unroll
            for (int ll2 = 0; ll2 < Pp; ll2++) {
                int kl2  = kk2 * Pp + ll2;
                int cell2 = kk2 * 10 + ll2 + wave;
                uint2 vv = *(const uint2*)&kvb[(cell2 * 48 + lane) * 2];
                uint4 A = ppw[kl2 * 2];
                uint4 B = ppw[kl2 * 2 + 1];
                o0 = fdot2(vv.y, A.y, fdot2(vv.x, A.x, o0));
                o1 = fdot2(vv.y, A.w, fdot2(vv.x, A.z, o1));
                o2 = fdot2(vv.y, B.y, fdot2(vv.x, B.x, o2));
                o3 = fdot2(vv.y, B.w, fdot2(vv.x, B.z, o3));
            }
        }
        Ot[((size_t)(b * Gg + 0) * HW + ij) * OC + h * MID + lane] = o0;
        Ot[((size_t)(b * Gg + 1) * HW + ij) * OC + h * MID + lane] = o1;
        Ot[((size_t)(b * Gg + 2) * HW + ij) * OC + h * MID + lane] = o2;
        Ot[((size_t)(b * Gg + 3) * HW + ij) * OC + h * MID + lane] = o3;
    }
}

// ---------------------------------------------------------------- kernel 3
__global__ __launch_bounds__(256) void outproj_kernel(const float* __restrict__ bout,
                                                      const float* __restrict__ ws,
                                                      float* __restrict__ out)
{
    __shared__ float ov[16 * 193];
    __shared__ float res[64 * 17];
    int tid = threadIdx.x;
    int p0 = blockIdx.x * 16;
    const float* Ot = ws + OOFF;

    for (int idx = tid; idx < 16 * OC; idx += 256) {
        int pl = idx / OC, t = idx % OC;
        ov[pl * 193 + t] = Ot[(size_t)(p0 + pl) * OC + t];
    }
    __syncthreads();

    int o = tid & 63, pg = tid >> 6;
    float a0 = bout[o], a1 = a0, a2 = a0, a3 = a0;
    for (int t = 0; t < OC; t++) {
        float w = g_WT2[t * 64 + o];
        a0 += w * ov[(pg     ) * 193 + t];
        a1 += w * ov[(pg +  4) * 193 + t];
        a2 += w * ov[(pg +  8) * 193 + t];
        a3 += w * ov[(pg + 12) * 193 + t];
    }
    res[o * 17 + pg     ] = a0;
    res[o * 17 + pg +  4] = a1;
    res[o * 17 + pg +  8] = a2;
    res[o * 17 + pg + 12] = a3;
    __syncthreads();

    for (int idx = tid; idx < 1024; idx += 256) {
        int o2 = idx >> 4, pl = idx & 15;
        int p = p0 + pl;
        int ij2 = p % HW; int bv = p / HW; int v = bv & 3; int bb = bv >> 2;
        out[((bb * COUT + o2) * Gg + v) * HW + ij2] = res[o2 * 17 + pl];
    }
}

// ---------------------------------------------------------------- launch
extern "C" void kernel_launch(void* const* d_in, const int* in_sizes, int n_in,
                              void* d_out, int out_size, void* d_ws, size_t ws_size,
                              hipStream_t stream)
{
    const float* x      = (const float*)d_in[0];
    const float* Wq     = (const float*)d_in[1];
    const float* bq     = (const float*)d_in[2];
    const float* Wk     = (const float*)d_in[3];
    const float* bk     = (const float*)d_in[4];
    const float* Wv     = (const float*)d_in[5];
    const float* bv     = (const float*)d_in[6];
    const float* Wout   = (const float*)d_in[7];
    const float* bout   = (const float*)d_in[8];
    const float* row_w1 = (const float*)d_in[9];
    const float* row_b1 = (const float*)d_in[10];
    const float* row_g  = (const float*)d_in[11];
    const float* row_bb = (const float*)d_in[12];
    const float* row_w2 = (const float*)d_in[13];
    const float* row_b2 = (const float*)d_in[14];
    const float* col_w1 = (const float*)d_in[15];
    const float* col_b1 = (const float*)d_in[16];
    const float* col_g  = (const float*)d_in[17];
    const float* col_bb = (const float*)d_in[18];
    const float* col_w2 = (const float*)d_in[19];
    const float* col_b2 = (const float*)d_in[20];
    const float* gemb   = (const float*)d_in[21];
    const float* ridx   = (const float*)d_in[22];
    const float* cidx   = (const float*)d_in[23];
    const int*   gidx   = (const int*)d_in[24];

    float* ws  = (float*)d_ws;
    float* out = (float*)d_out;

    qkvpe_kernel<<<Bb * Gg * Hh * 2 + 1, 192, 0, stream>>>(
        x, Wq, bq, Wk, bk, Wv, bv,
        row_w1, row_b1, row_g, row_bb, row_w2, row_b2,
        col_w1, col_b1, col_g, col_bb, col_w2, col_b2,
        ridx, cidx, gemb, gidx, Wout, ws);
    attn_kernel<<<Bb * NH * Hh * (Ww / 4), 256, 0, stream>>>(ws);
    outproj_kernel<<<Bb * Gg * HW / 16, 256, 0, stream>>>(bout, ws, out);
}